// Round 6
// baseline (157.179 us; speedup 1.0000x reference)
//
#include <hip/hip_runtime.h>
#include <stdint.h>

#define BATCH 128
#define NELEM 33600
#define HALF  16800
#define NCH   6
#define TOPK  300
#define NT1   1024
#define PT    17        // ceil(16800/1024)
#define CAP2  448       // candidate capacity (expect ~305-330)

__device__ __forceinline__ uint32_t fkey(float f) {
    uint32_t u = __float_as_uint(f);
    // order-preserving: descending float == descending unsigned key
    return (u & 0x80000000u) ? ~u : (u | 0x80000000u);
}

// One kernel: each block = one half-row. Phase A (validated R4 structure):
// exact local top-300, sorted, kept in LDS + mirrored to workspace.
// Phase B: last-of-pair (parity flag, device-scope atomic) merges the two
// sorted 300-lists by binary search and emits the transformed boxes.
__global__ __launch_bounds__(NT1) void yolo_fused(
    const float* __restrict__ preds, uint64_t* __restrict__ sorted_g,
    uint32_t* __restrict__ flags, float* __restrict__ out)
{
    const int blk  = blockIdx.x;      // 0..255
    const int b    = blk >> 1;
    const int seg  = blk & 1;
    const int tid  = threadIdx.x;
    const int lane = tid & 63;
    const int wave = tid >> 6;
    const float* row = preds + (size_t)b * (NELEM * NCH);
    const int base_i = seg * HALF;

    __shared__ uint32_t hist[16][257];   // stride 257: hot bin -> 16 distinct banks
    __shared__ uint32_t suf[256];
    __shared__ uint32_t h2[256];
    __shared__ __align__(16) uint64_t cand[CAP2 + 4];
    __shared__ uint64_t sMine[TOPK];
    __shared__ uint64_t sOther[TOPK];
    __shared__ uint32_t sh_b1, sh_S1, sh_thr, ccount, sh_old;

    for (int i = tid; i < 16 * 257; i += NT1) ((uint32_t*)hist)[i] = 0;
    if (tid == 0) ccount = 0;
    __syncthreads();

    // ---- load scores -> keys in regs + per-wave MSB histogram ----
    uint32_t key[PT];
    #pragma unroll
    for (int j = 0; j < PT; ++j) {
        int li = tid + j * NT1;
        if (li < HALF) {
            uint32_t k = fkey(row[(size_t)(base_i + li) * NCH + 4]);
            key[j] = k;
            atomicAdd(&hist[wave][k >> 24], 1u);
        } else key[j] = 0u;
    }
    __syncthreads();

    // ---- merge per-wave histograms ----
    if (tid < 256) {
        uint32_t s = 0;
        #pragma unroll
        for (int w = 0; w < 16; ++w) s += hist[w][tid];
        suf[tid] = s;
    }
    __syncthreads();

    // ---- suffix scan: suf[t] = count(bin >= t) ----
    for (int d = 1; d < 256; d <<= 1) {
        uint32_t t = 0;
        if (tid < 256 && tid + d < 256) t = suf[tid + d];
        __syncthreads();
        if (tid < 256) suf[tid] += t;
        __syncthreads();
    }
    if (tid < 256) {
        uint32_t hi = (tid == 255) ? 0u : suf[tid + 1];
        if (suf[tid] >= TOPK && hi < TOPK) { sh_b1 = (uint32_t)tid; sh_S1 = hi; }
        h2[tid] = 0;
    }
    __syncthreads();
    const uint32_t b1 = sh_b1, S1 = sh_S1;

    // ---- refine within bin b1 over key bits [23:16] ----
    #pragma unroll
    for (int j = 0; j < PT; ++j) {
        int li = tid + j * NT1;
        if (li < HALF && (key[j] >> 24) == b1)
            atomicAdd(&h2[(key[j] >> 16) & 0xFFu], 1u);
    }
    __syncthreads();
    for (int d = 1; d < 256; d <<= 1) {
        uint32_t t = 0;
        if (tid < 256 && tid + d < 256) t = h2[tid + d];
        __syncthreads();
        if (tid < 256) h2[tid] += t;
        __syncthreads();
    }
    if (tid < 256) {
        uint32_t hi = (tid == 255) ? 0u : h2[tid + 1];
        if (S1 + h2[tid] >= TOPK && S1 + hi < TOPK)
            sh_thr = (b1 << 8) | (uint32_t)tid;
    }
    __syncthreads();
    const uint32_t thr = sh_thr;

    // ---- collect candidates to LDS (wave-aggregated atomic) ----
    #pragma unroll
    for (int j = 0; j < PT; ++j) {
        int li = tid + j * NT1;
        bool pred = (li < HALF) && ((key[j] >> 16) >= thr);
        uint64_t m = __ballot(pred);
        if (m) {
            int leader = (int)__ffsll((long long)m) - 1;
            uint32_t base;
            if (lane == leader) base = atomicAdd(&ccount, (uint32_t)__popcll(m));
            base = __shfl(base, leader);
            if (pred) {
                uint32_t pos = base + (uint32_t)__popcll(m & ((1ull << lane) - 1ull));
                if (pos < CAP2)
                    cand[pos] = ((uint64_t)key[j] << 32)
                              | (uint32_t)(~(uint32_t)(base_i + li));
            }
        }
    }
    __syncthreads();
    const int Cn = (int)min(ccount, (uint32_t)CAP2);
    if (tid < 4) cand[Cn + tid] = 0ull;          // pad for paired reads
    __syncthreads();

    // ---- exact local rank (desc key, asc idx) via b128 broadcast reads ----
    if (tid < Cn) {
        const uint64_t mine = cand[tid];
        int rank = 0;
        const ulonglong2* c2 = (const ulonglong2*)cand;
        const int npair = (Cn + 1) >> 1;
        int p = 0;
        for (; p + 8 <= npair; p += 8) {
            #pragma unroll
            for (int u = 0; u < 8; ++u) {
                ulonglong2 v = c2[p + u];
                rank += (v.x > mine) ? 1 : 0;
                rank += (v.y > mine) ? 1 : 0;
            }
        }
        for (; p < npair; ++p) {
            ulonglong2 v = c2[p];
            rank += (v.x > mine) ? 1 : 0;
            rank += (v.y > mine) ? 1 : 0;
        }
        if (rank < TOPK) {
            sMine[rank] = mine;                              // keep for merge
            sorted_g[(size_t)blk * TOPK + rank] = mine;      // publish to sibling
        }
    }

    // ---- phase B: last-of-pair merges (parity flag survives graph replay) ----
    __threadfence();            // make sorted_g stores agent-visible (release)
    __syncthreads();
    if (tid == 0) sh_old = atomicAdd(&flags[b], 1u);   // device-scope (m20)
    __syncthreads();
    if ((sh_old & 1u) == 0u) return;    // first of the pair: done
    __threadfence();            // acquire side: sibling's stores now visible

    const int sib = blk ^ 1;
    if (tid < TOPK) sOther[tid] = sorted_g[(size_t)sib * TOPK + tid];
    __syncthreads();

    int i = -1; uint64_t mine = 0; const uint64_t* other = sMine;
    if (tid < TOPK)                          { i = tid;       mine = sMine[i];  other = sOther; }
    else if (tid >= 512 && tid < 512 + TOPK) { i = tid - 512; mine = sOther[i]; other = sMine;  }

    if (i >= 0) {
        // count of elements in `other` strictly greater than mine (desc sorted)
        int lo = 0, hi = TOPK;
        while (lo < hi) {
            int mid = (lo + hi) >> 1;
            if (other[mid] > mine) lo = mid + 1; else hi = mid;
        }
        int rank = i + lo;
        if (rank < TOPK) {
            uint32_t idx = ~(uint32_t)(mine & 0xFFFFFFFFu);
            const float* e = row + (size_t)idx * NCH;
            float p0 = e[0], p1 = e[1], p2 = e[2], p3 = e[3], p4 = e[4], p5 = e[5];
            const float inv = 1.0f / 1280.0f;
            float x1 = p0 * inv, y1 = p1 * inv, x2 = p2 * inv, y2 = p3 * inv;
            float* o = out + (size_t)b * (TOPK * NCH) + (size_t)rank * NCH;
            o[0] = (x1 + x2) * 0.5f;
            o[1] = (y1 + y2) * 0.5f;
            o[2] = x2 - x1;
            o[3] = y2 - y1;
            o[4] = p4;
            o[5] = p5;
        }
    }
}

extern "C" void kernel_launch(void* const* d_in, const int* in_sizes, int n_in,
                              void* d_out, int out_size, void* d_ws, size_t ws_size,
                              hipStream_t stream) {
    const float* preds = (const float*)d_in[0];
    float* out = (float*)d_out;
    // ws layout: sorted lists (256*300 u64 = 600 KiB) then 128 parity flags.
    // Flags are parity-based: each call adds exactly 2 per row, so any even
    // starting value (incl. 0xAAAAAAAA poison) is valid; no init needed.
    uint64_t* sorted_g = (uint64_t*)d_ws;
    uint32_t* flags = (uint32_t*)((char*)d_ws + (size_t)2 * BATCH * TOPK * sizeof(uint64_t));

    hipLaunchKernelGGL(yolo_fused, dim3(2 * BATCH), dim3(NT1), 0, stream,
                       preds, sorted_g, flags, out);
}

// Round 7
// 38.000 us; speedup vs baseline: 4.1363x; 4.1363x over previous
//
#include <hip/hip_runtime.h>
#include <stdint.h>

#define BATCH 128
#define NELEM 33600
#define NCH   6
#define TOPK  300
#define NT1   1024
#define CAP2  448       // candidate capacity (expect ~305-330)
#define NT2   1024

__device__ __forceinline__ uint32_t fkey(float f) {
    uint32_t u = __float_as_uint(f);
    // order-preserving: descending float == descending unsigned key
    return (u & 0x80000000u) ? ~u : (u | 0x80000000u);
}

// ---- kernel 1: per row-segment exact top-300, written sorted to ws ----
// Proven R4 structure; sizes templated. SEGS*SEGLEN == NELEM, PT*NT1 >= SEGLEN.
template<int SEGS, int SEGLEN, int PT>
__global__ __launch_bounds__(NT1, 8) void k1_select(
    const float* __restrict__ preds, uint64_t* __restrict__ sorted_g)
{
    const int blk  = blockIdx.x;            // 0 .. BATCH*SEGS-1
    const int b    = blk / SEGS;
    const int seg  = blk % SEGS;
    const int tid  = threadIdx.x;
    const int lane = tid & 63;
    const int wave = tid >> 6;
    const float* row = preds + (size_t)b * (NELEM * NCH);
    const int base_i = seg * SEGLEN;

    __shared__ uint32_t hist[16][257];   // stride 257: hot bin -> 16 distinct banks
    __shared__ uint32_t suf[256];
    __shared__ uint32_t h2[256];
    __shared__ __align__(16) uint64_t cand[CAP2 + 4];
    __shared__ uint32_t sh_b1, sh_S1, sh_thr, ccount;

    for (int i = tid; i < 16 * 257; i += NT1) ((uint32_t*)hist)[i] = 0;
    if (tid == 0) ccount = 0;
    __syncthreads();

    // ---- load scores -> keys in regs + per-wave MSB histogram ----
    uint32_t key[PT];
    #pragma unroll
    for (int j = 0; j < PT; ++j) {
        int li = tid + j * NT1;
        if (li < SEGLEN) {
            uint32_t k = fkey(row[(size_t)(base_i + li) * NCH + 4]);
            key[j] = k;
            atomicAdd(&hist[wave][k >> 24], 1u);
        } else key[j] = 0u;
    }
    __syncthreads();

    // ---- merge per-wave histograms ----
    if (tid < 256) {
        uint32_t s = 0;
        #pragma unroll
        for (int w = 0; w < 16; ++w) s += hist[w][tid];
        suf[tid] = s;
    }
    __syncthreads();

    // ---- suffix scan: suf[t] = count(bin >= t) ----
    for (int d = 1; d < 256; d <<= 1) {
        uint32_t t = 0;
        if (tid < 256 && tid + d < 256) t = suf[tid + d];
        __syncthreads();
        if (tid < 256) suf[tid] += t;
        __syncthreads();
    }
    if (tid < 256) {
        uint32_t hi = (tid == 255) ? 0u : suf[tid + 1];
        if (suf[tid] >= TOPK && hi < TOPK) { sh_b1 = (uint32_t)tid; sh_S1 = hi; }
        h2[tid] = 0;
    }
    __syncthreads();
    const uint32_t b1 = sh_b1, S1 = sh_S1;

    // ---- refine within bin b1 over key bits [23:16] ----
    #pragma unroll
    for (int j = 0; j < PT; ++j) {
        int li = tid + j * NT1;
        if (li < SEGLEN && (key[j] >> 24) == b1)
            atomicAdd(&h2[(key[j] >> 16) & 0xFFu], 1u);
    }
    __syncthreads();
    for (int d = 1; d < 256; d <<= 1) {
        uint32_t t = 0;
        if (tid < 256 && tid + d < 256) t = h2[tid + d];
        __syncthreads();
        if (tid < 256) h2[tid] += t;
        __syncthreads();
    }
    if (tid < 256) {
        uint32_t hi = (tid == 255) ? 0u : h2[tid + 1];
        if (S1 + h2[tid] >= TOPK && S1 + hi < TOPK)
            sh_thr = (b1 << 8) | (uint32_t)tid;
    }
    __syncthreads();
    const uint32_t thr = sh_thr;

    // ---- collect candidates to LDS (wave-aggregated atomic) ----
    #pragma unroll
    for (int j = 0; j < PT; ++j) {
        int li = tid + j * NT1;
        bool pred = (li < SEGLEN) && ((key[j] >> 16) >= thr);
        uint64_t m = __ballot(pred);
        if (m) {
            int leader = (int)__ffsll((long long)m) - 1;
            uint32_t base;
            if (lane == leader) base = atomicAdd(&ccount, (uint32_t)__popcll(m));
            base = __shfl(base, leader);
            if (pred) {
                uint32_t pos = base + (uint32_t)__popcll(m & ((1ull << lane) - 1ull));
                if (pos < CAP2)
                    cand[pos] = ((uint64_t)key[j] << 32)
                              | (uint32_t)(~(uint32_t)(base_i + li));
            }
        }
    }
    __syncthreads();
    const int Cn = (int)min(ccount, (uint32_t)CAP2);
    if (tid < 4) cand[Cn + tid] = 0ull;          // pad for paired reads
    __syncthreads();

    // ---- exact local rank (desc key, asc idx) via b128 broadcast reads ----
    if (tid < Cn) {
        const uint64_t mine = cand[tid];
        int rank = 0;
        const ulonglong2* c2 = (const ulonglong2*)cand;
        const int npair = (Cn + 1) >> 1;
        int p = 0;
        for (; p + 8 <= npair; p += 8) {
            #pragma unroll
            for (int u = 0; u < 8; ++u) {
                ulonglong2 v = c2[p + u];
                rank += (v.x > mine) ? 1 : 0;
                rank += (v.y > mine) ? 1 : 0;
            }
        }
        for (; p < npair; ++p) {
            ulonglong2 v = c2[p];
            rank += (v.x > mine) ? 1 : 0;
            rank += (v.y > mine) ? 1 : 0;
        }
        if (rank < TOPK)
            sorted_g[(size_t)blk * TOPK + rank] = mine;   // fills all 300 slots
    }
}

// ---- kernel 2: merge SEGS sorted 300-lists, emit transformed boxes ----
template<int SEGS>
__global__ __launch_bounds__(NT2) void k2_merge(
    const float* __restrict__ preds, const uint64_t* __restrict__ sorted_g,
    float* __restrict__ out)
{
    const int b   = blockIdx.x;
    const int tid = threadIdx.x;
    const int TOT = SEGS * TOPK;

    __shared__ uint64_t s[SEGS][TOPK];
    for (int e = tid; e < TOT; e += NT2)
        s[e / TOPK][e % TOPK] = sorted_g[(size_t)(b * SEGS) * TOPK + e];
    __syncthreads();

    for (int e = tid; e < TOT; e += NT2) {
        const int li = e / TOPK, i = e % TOPK;
        const uint64_t mine = s[li][i];
        int rank = i;
        #pragma unroll
        for (int l = 0; l < SEGS; ++l) {
            if (l == li) continue;
            // count of elements in s[l] strictly greater than mine (desc sorted)
            int lo = 0, hi = TOPK;
            while (lo < hi) {
                int mid = (lo + hi) >> 1;
                if (s[l][mid] > mine) lo = mid + 1; else hi = mid;
            }
            rank += lo;
        }
        if (rank < TOPK) {
            uint32_t idx = ~(uint32_t)(mine & 0xFFFFFFFFu);
            const float* e6 = preds + (size_t)b * (NELEM * NCH) + (size_t)idx * NCH;
            float p0 = e6[0], p1 = e6[1], p2 = e6[2], p3 = e6[3], p4 = e6[4], p5 = e6[5];
            const float inv = 1.0f / 1280.0f;
            float x1 = p0 * inv, y1 = p1 * inv, x2 = p2 * inv, y2 = p3 * inv;
            float* o = out + (size_t)b * (TOPK * NCH) + (size_t)rank * NCH;
            o[0] = (x1 + x2) * 0.5f;
            o[1] = (y1 + y2) * 0.5f;
            o[2] = x2 - x1;
            o[3] = y2 - y1;
            o[4] = p4;
            o[5] = p5;
        }
    }
}

extern "C" void kernel_launch(void* const* d_in, const int* in_sizes, int n_in,
                              void* d_out, int out_size, void* d_ws, size_t ws_size,
                              hipStream_t stream) {
    const float* preds = (const float*)d_in[0];
    float* out = (float*)d_out;
    uint64_t* sorted_g = (uint64_t*)d_ws;

    const size_t need4 = (size_t)4 * BATCH * TOPK * sizeof(uint64_t);  // 1.2 MiB
    if (ws_size >= need4) {
        // quarter-rows: grid 512 -> 2 blocks/CU, tails overlap loads
        hipLaunchKernelGGL((k1_select<4, 8400, 9>), dim3(4 * BATCH), dim3(NT1),
                           0, stream, preds, sorted_g);
        hipLaunchKernelGGL((k2_merge<4>), dim3(BATCH), dim3(NT2),
                           0, stream, preds, sorted_g, out);
    } else {
        // fallback: proven half-row config (R4), ws >= 600 KiB
        hipLaunchKernelGGL((k1_select<2, 16800, 17>), dim3(2 * BATCH), dim3(NT1),
                           0, stream, preds, sorted_g);
        hipLaunchKernelGGL((k2_merge<2>), dim3(BATCH), dim3(NT2),
                           0, stream, preds, sorted_g, out);
    }
}

// Round 8
// 32.683 us; speedup vs baseline: 4.8093x; 1.1627x over previous
//
#include <hip/hip_runtime.h>
#include <stdint.h>

#define BATCH 128
#define NELEM 33600
#define HALF  16800
#define NCH   6
#define TOPK  300
#define NT1   1024
#define PT    17        // ceil(16800/1024)
#define CAP2  448       // candidate capacity (expect ~305-330)
#define NT2   1024

__device__ __forceinline__ uint32_t fkey(float f) {
    uint32_t u = __float_as_uint(f);
    // order-preserving: descending float == descending unsigned key
    return (u & 0x80000000u) ? ~u : (u | 0x80000000u);
}

// ---- kernel 1: per half-row exact top-300, written sorted to ws ----
// R4 structure; both 256-bin suffix scans done in-register by wave 0
// (64 lanes x 4 bins + shfl_down suffix) -> ~8 barriers instead of ~40.
__global__ __launch_bounds__(NT1) void k1_select(
    const float* __restrict__ preds, uint64_t* __restrict__ sorted_g)
{
    const int blk  = blockIdx.x;      // 0..255
    const int b    = blk >> 1;
    const int seg  = blk & 1;
    const int tid  = threadIdx.x;
    const int lane = tid & 63;
    const int wave = tid >> 6;
    const float* row = preds + (size_t)b * (NELEM * NCH);
    const int base_i = seg * HALF;

    __shared__ uint32_t hist[16][257];   // stride 257: hot bin -> 16 distinct banks
    __shared__ __align__(16) uint32_t h2[256];
    __shared__ __align__(16) uint64_t cand[CAP2 + 4];
    __shared__ uint32_t sh_b1, sh_S1, sh_thr, ccount;

    for (int i = tid; i < 16 * 257; i += NT1) ((uint32_t*)hist)[i] = 0;
    if (tid < 256) h2[tid] = 0;
    if (tid == 0) ccount = 0;
    __syncthreads();                                   // B1

    // ---- load scores -> keys in regs + per-wave MSB histogram (fused:
    // atomics hide under load latency) ----
    uint32_t key[PT];
    #pragma unroll
    for (int j = 0; j < PT; ++j) {
        int li = tid + j * NT1;
        if (li < HALF) {
            uint32_t k = fkey(row[(size_t)(base_i + li) * NCH + 4]);
            key[j] = k;
            atomicAdd(&hist[wave][k >> 24], 1u);
        } else key[j] = 0u;
    }
    __syncthreads();                                   // B2

    // ---- wave0: merge 16 histograms + in-register suffix scan ----
    if (wave == 0) {
        uint32_t c0 = 0, c1 = 0, c2 = 0, c3 = 0;
        #pragma unroll
        for (int w = 0; w < 16; ++w) {
            c0 += hist[w][4 * lane + 0];
            c1 += hist[w][4 * lane + 1];
            c2 += hist[w][4 * lane + 2];
            c3 += hist[w][4 * lane + 3];
        }
        uint32_t T = c0 + c1 + c2 + c3;
        uint32_t ST = T;                 // inclusive suffix of lane totals
        #pragma unroll
        for (int d = 1; d < 64; d <<= 1) {
            uint32_t v = __shfl_down(ST, d);
            if (lane + d < 64) ST += v;
        }
        uint32_t hi = ST - T;            // suffix strictly after my 4 bins
        uint32_t S3 = hi + c3, S2 = S3 + c2, S1v = S2 + c1, S0 = S1v + c0;
        if (S0  >= TOPK && S1v < TOPK) { sh_b1 = 4u*lane;     sh_S1 = S1v; }
        if (S1v >= TOPK && S2  < TOPK) { sh_b1 = 4u*lane + 1; sh_S1 = S2;  }
        if (S2  >= TOPK && S3  < TOPK) { sh_b1 = 4u*lane + 2; sh_S1 = S3;  }
        if (S3  >= TOPK && hi  < TOPK) { sh_b1 = 4u*lane + 3; sh_S1 = hi;  }
    }
    __syncthreads();                                   // B3
    const uint32_t b1 = sh_b1, S1 = sh_S1;

    // ---- refine within bin b1 over key bits [23:16] (~400 elems) ----
    #pragma unroll
    for (int j = 0; j < PT; ++j) {
        int li = tid + j * NT1;
        if (li < HALF && (key[j] >> 24) == b1)
            atomicAdd(&h2[(key[j] >> 16) & 0xFFu], 1u);
    }
    __syncthreads();                                   // B4

    // ---- wave0: in-register suffix scan of h2, pick 16-bit threshold ----
    if (wave == 0) {
        uint4 v = *(const uint4*)&h2[4 * lane];
        uint32_t c0 = v.x, c1 = v.y, c2 = v.z, c3 = v.w;
        uint32_t T = c0 + c1 + c2 + c3;
        uint32_t ST = T;
        #pragma unroll
        for (int d = 1; d < 64; d <<= 1) {
            uint32_t t = __shfl_down(ST, d);
            if (lane + d < 64) ST += t;
        }
        uint32_t hi = ST - T;
        uint32_t S3 = hi + c3, S2 = S3 + c2, S1v = S2 + c1, S0 = S1v + c0;
        uint32_t base16 = b1 << 8;
        if (S1+S0  >= TOPK && S1+S1v < TOPK) sh_thr = base16 | (4u*lane);
        if (S1+S1v >= TOPK && S1+S2  < TOPK) sh_thr = base16 | (4u*lane + 1);
        if (S1+S2  >= TOPK && S1+S3  < TOPK) sh_thr = base16 | (4u*lane + 2);
        if (S1+S3  >= TOPK && S1+hi  < TOPK) sh_thr = base16 | (4u*lane + 3);
    }
    __syncthreads();                                   // B5
    const uint32_t thr = sh_thr;

    // ---- collect candidates to LDS (wave-aggregated atomic) ----
    #pragma unroll
    for (int j = 0; j < PT; ++j) {
        int li = tid + j * NT1;
        bool pred = (li < HALF) && ((key[j] >> 16) >= thr);
        uint64_t m = __ballot(pred);
        if (m) {
            int leader = (int)__ffsll((long long)m) - 1;
            uint32_t base;
            if (lane == leader) base = atomicAdd(&ccount, (uint32_t)__popcll(m));
            base = __shfl(base, leader);
            if (pred) {
                uint32_t pos = base + (uint32_t)__popcll(m & ((1ull << lane) - 1ull));
                if (pos < CAP2)
                    cand[pos] = ((uint64_t)key[j] << 32)
                              | (uint32_t)(~(uint32_t)(base_i + li));
            }
        }
    }
    __syncthreads();                                   // B6
    const int Cn = (int)min(ccount, (uint32_t)CAP2);
    if (tid < 4) cand[Cn + tid] = 0ull;          // pad for paired reads
    __syncthreads();                                   // B7

    // ---- exact local rank (desc key, asc idx) via b128 broadcast reads ----
    if (tid < Cn) {
        const uint64_t mine = cand[tid];
        int rank = 0;
        const ulonglong2* c2 = (const ulonglong2*)cand;
        const int npair = (Cn + 1) >> 1;
        int p = 0;
        for (; p + 8 <= npair; p += 8) {
            #pragma unroll
            for (int u = 0; u < 8; ++u) {
                ulonglong2 v = c2[p + u];
                rank += (v.x > mine) ? 1 : 0;
                rank += (v.y > mine) ? 1 : 0;
            }
        }
        for (; p < npair; ++p) {
            ulonglong2 v = c2[p];
            rank += (v.x > mine) ? 1 : 0;
            rank += (v.y > mine) ? 1 : 0;
        }
        if (rank < TOPK)
            sorted_g[(size_t)blk * TOPK + rank] = mine;   // fills all 300 slots
    }
}

// ---- kernel 2: merge two sorted 300-lists by binary search, emit boxes ----
__global__ __launch_bounds__(NT2) void k2_merge(
    const float* __restrict__ preds, const uint64_t* __restrict__ sorted_g,
    float* __restrict__ out)
{
    const int b   = blockIdx.x;
    const int tid = threadIdx.x;

    __shared__ uint64_t sA[TOPK], sB[TOPK];
    if (tid < TOPK)
        sA[tid] = sorted_g[(size_t)(2 * b) * TOPK + tid];
    else if (tid >= 512 && tid < 512 + TOPK)
        sB[tid - 512] = sorted_g[(size_t)(2 * b + 1) * TOPK + (tid - 512)];
    __syncthreads();

    int i = -1; uint64_t mine = 0; const uint64_t* other = sA;
    if (tid < TOPK)                          { i = tid;       mine = sA[i]; other = sB; }
    else if (tid >= 512 && tid < 512 + TOPK) { i = tid - 512; mine = sB[i]; other = sA; }

    if (i >= 0) {
        // count of elements in `other` strictly greater than mine (desc sorted)
        int lo = 0, hi = TOPK;
        while (lo < hi) {
            int mid = (lo + hi) >> 1;
            if (other[mid] > mine) lo = mid + 1; else hi = mid;
        }
        int rank = i + lo;
        if (rank < TOPK) {
            uint32_t idx = ~(uint32_t)(mine & 0xFFFFFFFFu);
            const float* e = preds + (size_t)b * (NELEM * NCH) + (size_t)idx * NCH;
            float p0 = e[0], p1 = e[1], p2 = e[2], p3 = e[3], p4 = e[4], p5 = e[5];
            const float inv = 1.0f / 1280.0f;
            float x1 = p0 * inv, y1 = p1 * inv, x2 = p2 * inv, y2 = p3 * inv;
            float* o = out + (size_t)b * (TOPK * NCH) + (size_t)rank * NCH;
            o[0] = (x1 + x2) * 0.5f;
            o[1] = (y1 + y2) * 0.5f;
            o[2] = x2 - x1;
            o[3] = y2 - y1;
            o[4] = p4;
            o[5] = p5;
        }
    }
}

extern "C" void kernel_launch(void* const* d_in, const int* in_sizes, int n_in,
                              void* d_out, int out_size, void* d_ws, size_t ws_size,
                              hipStream_t stream) {
    const float* preds = (const float*)d_in[0];
    float* out = (float*)d_out;
    uint64_t* sorted_g = (uint64_t*)d_ws;   // 256 * 300 * 8 B = 600 KiB

    hipLaunchKernelGGL(k1_select, dim3(2 * BATCH), dim3(NT1), 0, stream,
                       preds, sorted_g);
    hipLaunchKernelGGL(k2_merge, dim3(BATCH), dim3(NT2), 0, stream,
                       preds, sorted_g, out);
}